// Round 4
// baseline (249.546 us; speedup 1.0000x reference)
//
#include <hip/hip_runtime.h>
#include <hip/hip_bf16.h>
#include <math.h>

// LBGC: log-sigmoid TransR scoring.
// pos[b]  = softplus(-s_b),  s = dot(P_t u + time_t, poi_p)
// neg[ns] = sum_b softplus(+s_{ns,b})
//
// Pipeline (4 dispatches, no contended global atomics in hot paths):
//   k0: proj_emb fp32 -> bf16, pre-swizzled to LDS byte layout (ws)
//   k1: per-block histograms over t -> hcnt[T][NB]
//   k3: fused scan + scatter (each block redundantly scans L2-hot hcnt),
//       also zeroes neg accumulators + completion counter, writes offsets
//   k_main: per t-bin chunk, linear-copy staged bf16 P_t -> LDS; each wave
//       scores 16 samples via 32x mfma_f32_16x16x32_bf16; neg partials via
//       padded global atomics; last block writes out[B+ns].

typedef __attribute__((ext_vector_type(8))) short bfx8;
typedef __attribute__((ext_vector_type(4))) float f32x4;

#define CPB  4    // chunks (blocks) per t-bin
#define NTHR 256  // 4 waves per block

__device__ __forceinline__ float softplusf(float x) {
    return fmaxf(x, 0.f) + log1pf(expf(-fabsf(x)));
}

// f32 -> bf16 bits, round-to-nearest-even
__device__ __forceinline__ unsigned short f2bf(float f) {
    unsigned u = __float_as_uint(f);
    unsigned r = u + 0x7FFFu + ((u >> 16) & 1u);
    return (unsigned short)(r >> 16);
}

// ---------------- k0: convert P to bf16 in swizzled LDS layout ----------------
// For time slot t, row m, col c: byte offset within 32KB chunk =
//   m*256 + (2c ^ ((m&7)<<4))
__global__ __launch_bounds__(256) void k0_convert(const float* __restrict__ proj_emb,
                                                  unsigned short* __restrict__ pws) {
    const int t   = blockIdx.x;
    const int tid = threadIdx.x;
    const float* Pg = proj_emb + (size_t)t * 16384;
    char* dst = (char*)pws + (size_t)t * 32768;
    #pragma unroll
    for (int it = 0; it < 16; ++it) {
        int o = (it * 256 + tid) * 4;  // f32 index within 128x128
        float4 v = *(const float4*)(Pg + o);
        int m = o >> 7, c = o & 127;
        unsigned kb = (unsigned)(2 * c) ^ (((unsigned)m & 7u) << 4);
        unsigned lo = (unsigned)f2bf(v.x) | ((unsigned)f2bf(v.y) << 16);
        unsigned hi = (unsigned)f2bf(v.z) | ((unsigned)f2bf(v.w) << 16);
        *(uint2*)(dst + (size_t)m * 256 + kb) = make_uint2(lo, hi);
    }
}

// ---------------- k1: per-block histogram (no global atomics) ----------------
__global__ __launch_bounds__(1024) void k1_hist(
    const int* __restrict__ pos_t, const int* __restrict__ neg_t,
    int* __restrict__ hcnt, int B, int total, int T, int NB) {
    __shared__ int h[256];
    int tid = threadIdx.x;
    if (tid < 256) h[tid] = 0;
    __syncthreads();
    int s = blockIdx.x * 1024 + tid;
    if (s < total) {
        int t = (s < B) ? pos_t[s] : neg_t[s - B];
        atomicAdd(&h[t], 1);
    }
    __syncthreads();
    if (tid < T) hcnt[tid * NB + blockIdx.x] = h[tid];
}

// ---------------- k3: fused scan + scatter ----------------
__global__ __launch_bounds__(1024) void k3_scan_scatter(
    const int* __restrict__ pos_t, const int* __restrict__ neg_t,
    const int* __restrict__ hcnt, int* __restrict__ sorted,
    int* __restrict__ offsets, float* __restrict__ negpart, int* __restrict__ cnt,
    int B, int total, int T, int NB, int NS) {
    __shared__ int tmp[256];
    __shared__ int cur[256];
    int tid = threadIdx.x;
    int tot_ = 0, pre_ = 0;
    if (tid < T) {
        for (int b = 0; b < NB; ++b) {
            int v = hcnt[tid * NB + b];
            if (b < (int)blockIdx.x) pre_ += v;
            tot_ += v;
        }
    }
    if (tid < 256) tmp[tid] = tot_;
    __syncthreads();
    for (int d = 1; d < 256; d <<= 1) {
        int v = 0;
        if (tid < 256 && tid >= d) v = tmp[tid - d];
        __syncthreads();
        if (tid < 256) tmp[tid] += v;
        __syncthreads();
    }
    if (tid < T) {
        int excl = tmp[tid] - tot_;           // bin start
        cur[tid] = excl + pre_;               // this block's base in bin
        if (blockIdx.x == 0) {
            offsets[tid] = excl;
            if (tid == T - 1) offsets[T] = tmp[tid];
        }
    }
    if (blockIdx.x == 0) {
        if (tid >= 256 && tid < 256 + NS) negpart[(size_t)(tid - 256) * 64] = 0.f;
        if (tid == 512) *cnt = 0;
    }
    __syncthreads();
    int s = blockIdx.x * 1024 + tid;
    if (s < total) {
        int t = (s < B) ? pos_t[s] : neg_t[s - B];
        int r = atomicAdd(&cur[t], 1);
        sorted[r] = s;
    }
}

// ---------------- main scoring kernel (MFMA) ----------------
__global__ __launch_bounds__(NTHR) void k_main(
    const int* __restrict__ pos_u, const int* __restrict__ pos_p,
    const int* __restrict__ neg_u, const int* __restrict__ neg_p,
    const float* __restrict__ user_emb, const float* __restrict__ poi_emb,
    const float* __restrict__ time_emb, const unsigned short* __restrict__ pws,
    const int* __restrict__ offsets, const int* __restrict__ sorted,
    float* __restrict__ out, float* __restrict__ negpart, int* __restrict__ cnt,
    int B, int shiftB, int NS)
{
    __shared__ __align__(16) unsigned short ldsP[128 * 128];  // bf16, swizzled, 32 KiB
    __shared__ __align__(16) float ldsT[128];
    __shared__ float ldsNeg[4 * 16];
    __shared__ int ldsDone;

    const int t     = blockIdx.x / CPB;
    const int chunk = blockIdx.x % CPB;
    const int off   = offsets[t];
    const int end   = offsets[t + 1];
    const int tid   = threadIdx.x;
    const int wave  = tid >> 6;
    const int lane  = tid & 63;
    const int q     = lane >> 4;   // quad 0..3 (K-slice / C-row group)
    const int n     = lane & 15;   // sample slot / A-row within tile

    if (tid < 64) ldsNeg[tid] = 0.f;

    const bool has = (off + chunk * 16) < end;  // block-uniform
    if (has) {
        // linear copy of pre-swizzled bf16 P_t (32 KB)
        const uint4* src = (const uint4*)((const char*)pws + (size_t)t * 32768);
        uint4* dst = (uint4*)ldsP;
        #pragma unroll
        for (int it = 0; it < 8; ++it) dst[it * NTHR + tid] = src[it * NTHR + tid];
        if (tid < 128) ldsT[tid] = time_emb[(size_t)t * 128 + tid];
    }
    __syncthreads();

    if (has) {
        // wave w covers 16-sample tiles g_id = chunk + CPB*(w + 4*pass)
        for (int g = off + 16 * (chunk + CPB * wave); g < end; g += 16 * CPB * 4) {
            int p = g + n;
            bool actv = (p < end);
            int sv = sorted[actv ? p : (end - 1)];
            int uidx, pidx;
            if (sv < B) { uidx = pos_u[sv]; pidx = pos_p[sv]; }
            else        { int r = sv - B; uidx = neg_u[r]; pidx = neg_p[r]; }

            // B-fragments: u row -> bf16, lane holds k = kk*32 + q*8 .. +7
            const float* up = user_emb + (size_t)uidx * 128;
            bfx8 ub[4];
            #pragma unroll
            for (int kk = 0; kk < 4; ++kk) {
                const float* usrc = up + kk * 32 + q * 8;
                float4 a = *(const float4*)(usrc);
                float4 b = *(const float4*)(usrc + 4);
                bfx8 f;
                f[0] = (short)f2bf(a.x); f[1] = (short)f2bf(a.y);
                f[2] = (short)f2bf(a.z); f[3] = (short)f2bf(a.w);
                f[4] = (short)f2bf(b.x); f[5] = (short)f2bf(b.y);
                f[6] = (short)f2bf(b.z); f[7] = (short)f2bf(b.w);
                ub[kk] = f;
            }

            f32x4 acc[8];
            #pragma unroll
            for (int mt = 0; mt < 8; ++mt) acc[mt] = (f32x4)(0.f);

            // V = P * U : 8 M-tiles x 4 K-steps
            #pragma unroll
            for (int mt = 0; mt < 8; ++mt) {
                #pragma unroll
                for (int kk = 0; kk < 4; ++kk) {
                    unsigned kb = (unsigned)(kk * 64 + q * 16) ^ (((unsigned)n & 7u) << 4);
                    bfx8 af = *(const bfx8*)((const char*)ldsP + (size_t)(mt * 16 + n) * 256 + kb);
                    acc[mt] = __builtin_amdgcn_mfma_f32_16x16x32_bf16(af, ub[kk], acc[mt], 0, 0, 0);
                }
            }

            // epilogue: score = sum_m (V[m][n] + time[m]) * poi[m]
            // C/D layout: col = lane&15 (sample), row = (lane>>4)*4 + reg
            const float* pp = poi_emb + (size_t)pidx * 128;
            float part = 0.f;
            #pragma unroll
            for (int mt = 0; mt < 8; ++mt) {
                int mo = mt * 16 + q * 4;
                float4 pv = *(const float4*)(pp + mo);
                float4 tv = *(const float4*)(ldsT + mo);
                part += (acc[mt][0] + tv.x) * pv.x;
                part += (acc[mt][1] + tv.y) * pv.y;
                part += (acc[mt][2] + tv.z) * pv.z;
                part += (acc[mt][3] + tv.w) * pv.w;
            }
            part += __shfl_xor(part, 16, 64);
            part += __shfl_xor(part, 32, 64);

            if (actv && q == 0) {
                if (sv < B) out[sv] = softplusf(-part);
                else atomicAdd(&ldsNeg[wave * 16 + ((sv - B) >> shiftB)], softplusf(part));
            }
        }
    }
    __syncthreads();

    // flush per-block neg partials to padded global slots
    if (tid < NS) {
        float s = ldsNeg[tid] + ldsNeg[16 + tid] + ldsNeg[32 + tid] + ldsNeg[48 + tid];
        atomicAdd(&negpart[(size_t)tid * 64], s);
    }
    __threadfence();
    __syncthreads();
    if (tid == 0) ldsDone = (atomicAdd(cnt, 1) == (int)gridDim.x - 1);
    __syncthreads();
    if (ldsDone && tid < NS) {
        __threadfence();
        out[B + tid] = atomicAdd(&negpart[(size_t)tid * 64], 0.f);  // coherent read
    }
}

extern "C" void kernel_launch(void* const* d_in, const int* in_sizes, int n_in,
                              void* d_out, int out_size, void* d_ws, size_t ws_size,
                              hipStream_t stream) {
    const int*   pos_u    = (const int*)d_in[0];
    const int*   pos_t    = (const int*)d_in[1];
    const int*   pos_p    = (const int*)d_in[2];
    const int*   neg_u    = (const int*)d_in[3];
    const int*   neg_t    = (const int*)d_in[4];
    const int*   neg_p    = (const int*)d_in[5];
    const float* user_emb = (const float*)d_in[7];
    const float* poi_emb  = (const float*)d_in[8];
    const float* time_emb = (const float*)d_in[9];
    const float* proj_emb = (const float*)d_in[10];
    float* out = (float*)d_out;

    const int B     = in_sizes[0];           // 4096
    const int NS    = in_sizes[3] / B;       // 10
    const int total = B + NS * B;            // 45056
    const int T     = in_sizes[9] / 128;     // 168 time slots
    const int NB    = (total + 1023) / 1024; // preprocessing blocks (44)

    int shiftB = 0;
    while ((1 << shiftB) < B) shiftB++;      // B = 4096 (pow2)

    const int gridN = T * CPB;               // k_main grid (672)

    // workspace layout (pws first: 16B-aligned)
    unsigned short* pws = (unsigned short*)d_ws;          // [T*16384] bf16, swizzled
    int* ws_i    = (int*)((char*)d_ws + (size_t)T * 32768);
    int* hcnt    = ws_i;                                  // [T*NB]
    int* offsets = hcnt + T * NB;                         // [T+1]
    int* sorted  = offsets + T + 1;                       // [total]
    int* cnt     = sorted + total;                        // [1]
    float* negpart = (float*)(cnt + 4);                   // [NS*64] padded

    k0_convert<<<T, 256, 0, stream>>>(proj_emb, pws);
    k1_hist<<<NB, 1024, 0, stream>>>(pos_t, neg_t, hcnt, B, total, T, NB);
    k3_scan_scatter<<<NB, 1024, 0, stream>>>(pos_t, neg_t, hcnt, sorted,
                                             offsets, negpart, cnt,
                                             B, total, T, NB, NS);
    k_main<<<gridN, NTHR, 0, stream>>>(pos_u, pos_p, neg_u, neg_p,
                                       user_emb, poi_emb, time_emb, pws,
                                       offsets, sorted, out, negpart, cnt,
                                       B, shiftB, NS);
}

// Round 9
// 175.580 us; speedup vs baseline: 1.4213x; 1.4213x over previous
//
#include <hip/hip_runtime.h>
#include <hip/hip_bf16.h>
#include <math.h>

// LBGC: log-sigmoid TransR scoring.
// pos[b]  = softplus(-s_b),  s = dot(P_t u + time_t, poi_p)
// neg[ns] = sum_b softplus(+s_{ns,b})
//
// Pipeline (5 dispatches, no device-scope fences, no contended global atomics):
//   k0: proj_emb fp32 -> bf16, pre-swizzled to LDS byte layout (ws)
//   k1: per-block histograms over t -> hcnt[T][NB]
//   k3: fused scan + scatter (each block redundantly scans L2-hot hcnt)
//   k_main: per t-bin chunk, linear-copy staged bf16 P_t -> LDS; each wave
//           scores 16 samples via 32x mfma_f32_16x16x32_bf16; neg partials
//           stored plainly to negpart[ns][block]  (NO atomics / fences)
//   k_reduce: sum per-block neg partials (one block per ns).

typedef __attribute__((ext_vector_type(8))) short bfx8;
typedef __attribute__((ext_vector_type(4))) float f32x4;

#define CPB  4    // chunks (blocks) per t-bin
#define NTHR 256  // 4 waves per block

__device__ __forceinline__ float softplusf(float x) {
    return fmaxf(x, 0.f) + log1pf(expf(-fabsf(x)));
}

// f32 -> bf16 bits, round-to-nearest-even
__device__ __forceinline__ unsigned short f2bf(float f) {
    unsigned u = __float_as_uint(f);
    unsigned r = u + 0x7FFFu + ((u >> 16) & 1u);
    return (unsigned short)(r >> 16);
}

// ---------------- k0: convert P to bf16 in swizzled LDS layout ----------------
// For time slot t, row m, col c: byte offset within 32KB chunk =
//   m*256 + (2c ^ ((m&7)<<4))
__global__ __launch_bounds__(256) void k0_convert(const float* __restrict__ proj_emb,
                                                  unsigned short* __restrict__ pws) {
    const int t   = blockIdx.x;
    const int tid = threadIdx.x;
    const float* Pg = proj_emb + (size_t)t * 16384;
    char* dst = (char*)pws + (size_t)t * 32768;
    #pragma unroll
    for (int it = 0; it < 16; ++it) {
        int o = (it * 256 + tid) * 4;  // f32 index within 128x128
        float4 v = *(const float4*)(Pg + o);
        int m = o >> 7, c = o & 127;
        unsigned kb = (unsigned)(2 * c) ^ (((unsigned)m & 7u) << 4);
        unsigned lo = (unsigned)f2bf(v.x) | ((unsigned)f2bf(v.y) << 16);
        unsigned hi = (unsigned)f2bf(v.z) | ((unsigned)f2bf(v.w) << 16);
        *(uint2*)(dst + (size_t)m * 256 + kb) = make_uint2(lo, hi);
    }
}

// ---------------- k1: per-block histogram (no global atomics) ----------------
__global__ __launch_bounds__(1024) void k1_hist(
    const int* __restrict__ pos_t, const int* __restrict__ neg_t,
    int* __restrict__ hcnt, int B, int total, int T, int NB) {
    __shared__ int h[256];
    int tid = threadIdx.x;
    if (tid < 256) h[tid] = 0;
    __syncthreads();
    int s = blockIdx.x * 1024 + tid;
    if (s < total) {
        int t = (s < B) ? pos_t[s] : neg_t[s - B];
        atomicAdd(&h[t], 1);
    }
    __syncthreads();
    if (tid < T) hcnt[tid * NB + blockIdx.x] = h[tid];
}

// ---------------- k3: fused scan + scatter ----------------
__global__ __launch_bounds__(1024) void k3_scan_scatter(
    const int* __restrict__ pos_t, const int* __restrict__ neg_t,
    const int* __restrict__ hcnt, int* __restrict__ sorted,
    int* __restrict__ offsets,
    int B, int total, int T, int NB) {
    __shared__ int tmp[256];
    __shared__ int cur[256];
    int tid = threadIdx.x;
    int tot_ = 0, pre_ = 0;
    if (tid < T) {
        for (int b = 0; b < NB; ++b) {
            int v = hcnt[tid * NB + b];
            if (b < (int)blockIdx.x) pre_ += v;
            tot_ += v;
        }
    }
    if (tid < 256) tmp[tid] = tot_;
    __syncthreads();
    for (int d = 1; d < 256; d <<= 1) {
        int v = 0;
        if (tid < 256 && tid >= d) v = tmp[tid - d];
        __syncthreads();
        if (tid < 256) tmp[tid] += v;
        __syncthreads();
    }
    if (tid < T) {
        int excl = tmp[tid] - tot_;           // bin start
        cur[tid] = excl + pre_;               // this block's base in bin
        if (blockIdx.x == 0) {
            offsets[tid] = excl;
            if (tid == T - 1) offsets[T] = tmp[tid];
        }
    }
    __syncthreads();
    int s = blockIdx.x * 1024 + tid;
    if (s < total) {
        int t = (s < B) ? pos_t[s] : neg_t[s - B];
        int r = atomicAdd(&cur[t], 1);
        sorted[r] = s;
    }
}

// ---------------- main scoring kernel (MFMA) ----------------
__global__ __launch_bounds__(NTHR) void k_main(
    const int* __restrict__ pos_u, const int* __restrict__ pos_p,
    const int* __restrict__ neg_u, const int* __restrict__ neg_p,
    const float* __restrict__ user_emb, const float* __restrict__ poi_emb,
    const float* __restrict__ time_emb, const unsigned short* __restrict__ pws,
    const int* __restrict__ offsets, const int* __restrict__ sorted,
    float* __restrict__ out, float* __restrict__ negpart,
    int B, int shiftB, int NS, int gridN)
{
    __shared__ __align__(16) unsigned short ldsP[128 * 128];  // bf16, swizzled, 32 KiB
    __shared__ __align__(16) float ldsT[128];
    __shared__ float ldsNeg[4 * 16];

    const int t     = blockIdx.x / CPB;
    const int chunk = blockIdx.x % CPB;
    const int off   = offsets[t];
    const int end   = offsets[t + 1];
    const int tid   = threadIdx.x;
    const int wave  = tid >> 6;
    const int lane  = tid & 63;
    const int q     = lane >> 4;   // quad 0..3 (K-slice / C-row group)
    const int n     = lane & 15;   // sample slot / A-row within tile

    if (tid < 64) ldsNeg[tid] = 0.f;

    const bool has = (off + chunk * 16) < end;  // block-uniform
    if (has) {
        // linear copy of pre-swizzled bf16 P_t (32 KB)
        const uint4* src = (const uint4*)((const char*)pws + (size_t)t * 32768);
        uint4* dst = (uint4*)ldsP;
        #pragma unroll
        for (int it = 0; it < 8; ++it) dst[it * NTHR + tid] = src[it * NTHR + tid];
        if (tid < 128) ldsT[tid] = time_emb[(size_t)t * 128 + tid];
    }
    __syncthreads();

    if (has) {
        // wave w covers 16-sample tiles g_id = chunk + CPB*(w + 4*pass)
        for (int g = off + 16 * (chunk + CPB * wave); g < end; g += 16 * CPB * 4) {
            int p = g + n;
            bool actv = (p < end);
            int sv = sorted[actv ? p : (end - 1)];
            int uidx, pidx;
            if (sv < B) { uidx = pos_u[sv]; pidx = pos_p[sv]; }
            else        { int r = sv - B; uidx = neg_u[r]; pidx = neg_p[r]; }

            // B-fragments: u row -> bf16, lane holds k = kk*32 + q*8 .. +7
            const float* up = user_emb + (size_t)uidx * 128;
            bfx8 ub[4];
            #pragma unroll
            for (int kk = 0; kk < 4; ++kk) {
                const float* usrc = up + kk * 32 + q * 8;
                float4 a = *(const float4*)(usrc);
                float4 b = *(const float4*)(usrc + 4);
                bfx8 f;
                f[0] = (short)f2bf(a.x); f[1] = (short)f2bf(a.y);
                f[2] = (short)f2bf(a.z); f[3] = (short)f2bf(a.w);
                f[4] = (short)f2bf(b.x); f[5] = (short)f2bf(b.y);
                f[6] = (short)f2bf(b.z); f[7] = (short)f2bf(b.w);
                ub[kk] = f;
            }

            f32x4 acc[8];
            #pragma unroll
            for (int mt = 0; mt < 8; ++mt) acc[mt] = (f32x4)(0.f);

            // V = P * U : 8 M-tiles x 4 K-steps
            #pragma unroll
            for (int mt = 0; mt < 8; ++mt) {
                #pragma unroll
                for (int kk = 0; kk < 4; ++kk) {
                    unsigned kb = (unsigned)(kk * 64 + q * 16) ^ (((unsigned)n & 7u) << 4);
                    bfx8 af = *(const bfx8*)((const char*)ldsP + (size_t)(mt * 16 + n) * 256 + kb);
                    acc[mt] = __builtin_amdgcn_mfma_f32_16x16x32_bf16(af, ub[kk], acc[mt], 0, 0, 0);
                }
            }

            // epilogue: score = sum_m (V[m][n] + time[m]) * poi[m]
            // C/D layout: col = lane&15 (sample), row = (lane>>4)*4 + reg
            const float* pp = poi_emb + (size_t)pidx * 128;
            float part = 0.f;
            #pragma unroll
            for (int mt = 0; mt < 8; ++mt) {
                int mo = mt * 16 + q * 4;
                float4 pv = *(const float4*)(pp + mo);
                float4 tv = *(const float4*)(ldsT + mo);
                part += (acc[mt][0] + tv.x) * pv.x;
                part += (acc[mt][1] + tv.y) * pv.y;
                part += (acc[mt][2] + tv.z) * pv.z;
                part += (acc[mt][3] + tv.w) * pv.w;
            }
            part += __shfl_xor(part, 16, 64);
            part += __shfl_xor(part, 32, 64);

            if (actv && q == 0) {
                if (sv < B) out[sv] = softplusf(-part);
                else atomicAdd(&ldsNeg[wave * 16 + ((sv - B) >> shiftB)], softplusf(part));
            }
        }
    }
    __syncthreads();

    // plain per-block partial stores (ws poisoned -> every block must write)
    if (tid < NS) {
        float s = ldsNeg[tid] + ldsNeg[16 + tid] + ldsNeg[32 + tid] + ldsNeg[48 + tid];
        negpart[(size_t)tid * gridN + blockIdx.x] = s;
    }
}

// ---------------- final neg reduction (one block per ns) ----------------
__global__ void k_reduce(const float* __restrict__ negpart, float* __restrict__ out,
                         int B, int gridN) {
    __shared__ float red[256];
    int ns = blockIdx.x;
    float acc = 0.f;
    for (int r = threadIdx.x; r < gridN; r += 256)
        acc += negpart[(size_t)ns * gridN + r];
    red[threadIdx.x] = acc;
    __syncthreads();
    for (int s2 = 128; s2 > 0; s2 >>= 1) {
        if (threadIdx.x < s2) red[threadIdx.x] += red[threadIdx.x + s2];
        __syncthreads();
    }
    if (threadIdx.x == 0) out[B + ns] = red[0];
}

extern "C" void kernel_launch(void* const* d_in, const int* in_sizes, int n_in,
                              void* d_out, int out_size, void* d_ws, size_t ws_size,
                              hipStream_t stream) {
    const int*   pos_u    = (const int*)d_in[0];
    const int*   pos_t    = (const int*)d_in[1];
    const int*   pos_p    = (const int*)d_in[2];
    const int*   neg_u    = (const int*)d_in[3];
    const int*   neg_t    = (const int*)d_in[4];
    const int*   neg_p    = (const int*)d_in[5];
    const float* user_emb = (const float*)d_in[7];
    const float* poi_emb  = (const float*)d_in[8];
    const float* time_emb = (const float*)d_in[9];
    const float* proj_emb = (const float*)d_in[10];
    float* out = (float*)d_out;

    const int B     = in_sizes[0];           // 4096
    const int NS    = in_sizes[3] / B;       // 10
    const int total = B + NS * B;            // 45056
    const int T     = in_sizes[9] / 128;     // 168 time slots
    const int NB    = (total + 1023) / 1024; // preprocessing blocks (44)

    int shiftB = 0;
    while ((1 << shiftB) < B) shiftB++;      // B = 4096 (pow2)

    const int gridN = T * CPB;               // k_main grid (672)

    // workspace layout (pws first: 16B-aligned)
    unsigned short* pws = (unsigned short*)d_ws;          // [T*16384] bf16, swizzled
    int* ws_i    = (int*)((char*)d_ws + (size_t)T * 32768);
    int* hcnt    = ws_i;                                  // [T*NB]
    int* offsets = hcnt + T * NB;                         // [T+1]
    int* sorted  = offsets + T + 1;                       // [total]
    float* negpart = (float*)(sorted + total);            // [NS][gridN]

    k0_convert<<<T, 256, 0, stream>>>(proj_emb, pws);
    k1_hist<<<NB, 1024, 0, stream>>>(pos_t, neg_t, hcnt, B, total, T, NB);
    k3_scan_scatter<<<NB, 1024, 0, stream>>>(pos_t, neg_t, hcnt, sorted,
                                             offsets, B, total, T, NB);
    k_main<<<gridN, NTHR, 0, stream>>>(pos_u, pos_p, neg_u, neg_p,
                                       user_emb, poi_emb, time_emb, pws,
                                       offsets, sorted, out, negpart,
                                       B, shiftB, NS, gridN);
    k_reduce<<<NS, 256, 0, stream>>>(negpart, out, B, gridN);
}

// Round 10
// 166.246 us; speedup vs baseline: 1.5011x; 1.0561x over previous
//
#include <hip/hip_runtime.h>
#include <hip/hip_bf16.h>
#include <math.h>

// LBGC: log-sigmoid TransR scoring.
// pos[b]  = softplus(-s_b),  s = dot(P_t u + time_t, poi_p)
// neg[ns] = sum_b softplus(+s_{ns,b})
//
// Pipeline (4 dispatches, no device-scope fences, no contended global atomics):
//   k01: proj_emb fp32 -> bf16 pre-swizzled to LDS byte layout (all 168 blocks)
//        + per-block t-histograms (blocks < NB)
//   k3 : fused scan + scatter (each block redundantly scans L2-hot hcnt)
//   k_main: per t-bin chunk, linear-copy staged bf16 P_t -> LDS; each wave
//           scores 16 samples via 32x mfma_f32_16x16x32_bf16; neg partials
//           stored plainly to negpart[ns][block]
//   k_reduce: sum per-block neg partials (one block per ns).

typedef __attribute__((ext_vector_type(8))) short bfx8;
typedef __attribute__((ext_vector_type(4))) float f32x4;

#define CPB  6    // chunks (blocks) per t-bin
#define NTHR 256  // 4 waves per block (k_main)

__device__ __forceinline__ float softplusf(float x) {
    return fmaxf(x, 0.f) + log1pf(expf(-fabsf(x)));
}

// f32 -> bf16 bits, round-to-nearest-even
__device__ __forceinline__ unsigned short f2bf(float f) {
    unsigned u = __float_as_uint(f);
    unsigned r = u + 0x7FFFu + ((u >> 16) & 1u);
    return (unsigned short)(r >> 16);
}

// ---------------- k01: P conversion (+ histogram on low blocks) ----------------
// Convert: block t: row m, col c -> byte m*256 + (2c ^ ((m&7)<<4)) in 32KB chunk.
// Hist: blocks < NB also histogram their 1024-sample slice into hcnt[T][NB].
__global__ __launch_bounds__(1024) void k01_convert_hist(
    const float* __restrict__ proj_emb, unsigned short* __restrict__ pws,
    const int* __restrict__ pos_t, const int* __restrict__ neg_t,
    int* __restrict__ hcnt, int B, int total, int T, int NB) {
    __shared__ int h[256];
    const int t   = blockIdx.x;
    const int tid = threadIdx.x;

    if (tid < 256) h[tid] = 0;

    const float* Pg = proj_emb + (size_t)t * 16384;
    char* dst = (char*)pws + (size_t)t * 32768;
    #pragma unroll
    for (int it = 0; it < 4; ++it) {
        int o = (it * 1024 + tid) * 4;  // f32 index within 128x128
        float4 v = *(const float4*)(Pg + o);
        int m = o >> 7, c = o & 127;
        unsigned kb = (unsigned)(2 * c) ^ (((unsigned)m & 7u) << 4);
        unsigned lo = (unsigned)f2bf(v.x) | ((unsigned)f2bf(v.y) << 16);
        unsigned hi = (unsigned)f2bf(v.z) | ((unsigned)f2bf(v.w) << 16);
        *(uint2*)(dst + (size_t)m * 256 + kb) = make_uint2(lo, hi);
    }

    __syncthreads();
    if (blockIdx.x < (unsigned)NB) {
        int s = blockIdx.x * 1024 + tid;
        if (s < total) {
            int tt = (s < B) ? pos_t[s] : neg_t[s - B];
            atomicAdd(&h[tt], 1);
        }
    }
    __syncthreads();
    if (blockIdx.x < (unsigned)NB && tid < T) hcnt[tid * NB + blockIdx.x] = h[tid];
}

// ---------------- k3: fused scan + scatter ----------------
__global__ __launch_bounds__(1024) void k3_scan_scatter(
    const int* __restrict__ pos_t, const int* __restrict__ neg_t,
    const int* __restrict__ hcnt, int* __restrict__ sorted,
    int* __restrict__ offsets,
    int B, int total, int T, int NB) {
    __shared__ int tmp[256];
    __shared__ int cur[256];
    int tid = threadIdx.x;
    int tot_ = 0, pre_ = 0;
    if (tid < T) {
        for (int b = 0; b < NB; ++b) {
            int v = hcnt[tid * NB + b];
            if (b < (int)blockIdx.x) pre_ += v;
            tot_ += v;
        }
    }
    if (tid < 256) tmp[tid] = tot_;
    __syncthreads();
    for (int d = 1; d < 256; d <<= 1) {
        int v = 0;
        if (tid < 256 && tid >= d) v = tmp[tid - d];
        __syncthreads();
        if (tid < 256) tmp[tid] += v;
        __syncthreads();
    }
    if (tid < T) {
        int excl = tmp[tid] - tot_;           // bin start
        cur[tid] = excl + pre_;               // this block's base in bin
        if (blockIdx.x == 0) {
            offsets[tid] = excl;
            if (tid == T - 1) offsets[T] = tmp[tid];
        }
    }
    __syncthreads();
    int s = blockIdx.x * 1024 + tid;
    if (s < total) {
        int t = (s < B) ? pos_t[s] : neg_t[s - B];
        int r = atomicAdd(&cur[t], 1);
        sorted[r] = s;
    }
}

// ---------------- main scoring kernel (MFMA) ----------------
__global__ __launch_bounds__(NTHR) void k_main(
    const int* __restrict__ pos_u, const int* __restrict__ pos_p,
    const int* __restrict__ neg_u, const int* __restrict__ neg_p,
    const float* __restrict__ user_emb, const float* __restrict__ poi_emb,
    const float* __restrict__ time_emb, const unsigned short* __restrict__ pws,
    const int* __restrict__ offsets, const int* __restrict__ sorted,
    float* __restrict__ out, float* __restrict__ negpart,
    int B, int shiftB, int NS, int gridN)
{
    __shared__ __align__(16) unsigned short ldsP[128 * 128];  // bf16, swizzled, 32 KiB
    __shared__ __align__(16) float ldsT[128];
    __shared__ float ldsNeg[4 * 16];

    const int t     = blockIdx.x / CPB;
    const int chunk = blockIdx.x % CPB;
    const int off   = offsets[t];
    const int end   = offsets[t + 1];
    const int tid   = threadIdx.x;
    const int wave  = tid >> 6;
    const int lane  = tid & 63;
    const int q     = lane >> 4;   // quad 0..3 (K-slice / C-row group)
    const int n     = lane & 15;   // sample slot / A-row within tile

    if (tid < 64) ldsNeg[tid] = 0.f;

    const bool has = (off + chunk * 16) < end;  // block-uniform
    if (has) {
        // linear copy of pre-swizzled bf16 P_t (32 KB)
        const uint4* src = (const uint4*)((const char*)pws + (size_t)t * 32768);
        uint4* dst = (uint4*)ldsP;
        #pragma unroll
        for (int it = 0; it < 8; ++it) dst[it * NTHR + tid] = src[it * NTHR + tid];
        if (tid < 128) ldsT[tid] = time_emb[(size_t)t * 128 + tid];
    }
    __syncthreads();

    if (has) {
        // wave w covers 16-sample tiles g_id = chunk + CPB*(w + 4*pass)
        for (int g = off + 16 * (chunk + CPB * wave); g < end; g += 16 * CPB * 4) {
            int p = g + n;
            bool actv = (p < end);
            int sv = sorted[actv ? p : (end - 1)];
            int uidx, pidx;
            if (sv < B) { uidx = pos_u[sv]; pidx = pos_p[sv]; }
            else        { int r = sv - B; uidx = neg_u[r]; pidx = neg_p[r]; }

            // B-fragments: u row -> bf16, lane holds k = kk*32 + q*8 .. +7
            const float* up = user_emb + (size_t)uidx * 128;
            bfx8 ub[4];
            #pragma unroll
            for (int kk = 0; kk < 4; ++kk) {
                const float* usrc = up + kk * 32 + q * 8;
                float4 a = *(const float4*)(usrc);
                float4 b = *(const float4*)(usrc + 4);
                bfx8 f;
                f[0] = (short)f2bf(a.x); f[1] = (short)f2bf(a.y);
                f[2] = (short)f2bf(a.z); f[3] = (short)f2bf(a.w);
                f[4] = (short)f2bf(b.x); f[5] = (short)f2bf(b.y);
                f[6] = (short)f2bf(b.z); f[7] = (short)f2bf(b.w);
                ub[kk] = f;
            }

            f32x4 acc[8];
            #pragma unroll
            for (int mt = 0; mt < 8; ++mt) acc[mt] = (f32x4)(0.f);

            // V = P * U : 8 M-tiles x 4 K-steps
            #pragma unroll
            for (int mt = 0; mt < 8; ++mt) {
                #pragma unroll
                for (int kk = 0; kk < 4; ++kk) {
                    unsigned kb = (unsigned)(kk * 64 + q * 16) ^ (((unsigned)n & 7u) << 4);
                    bfx8 af = *(const bfx8*)((const char*)ldsP + (size_t)(mt * 16 + n) * 256 + kb);
                    acc[mt] = __builtin_amdgcn_mfma_f32_16x16x32_bf16(af, ub[kk], acc[mt], 0, 0, 0);
                }
            }

            // epilogue: score = sum_m (V[m][n] + time[m]) * poi[m]
            // C/D layout: col = lane&15 (sample), row = (lane>>4)*4 + reg
            const float* pp = poi_emb + (size_t)pidx * 128;
            float part = 0.f;
            #pragma unroll
            for (int mt = 0; mt < 8; ++mt) {
                int mo = mt * 16 + q * 4;
                float4 pv = *(const float4*)(pp + mo);
                float4 tv = *(const float4*)(ldsT + mo);
                part += (acc[mt][0] + tv.x) * pv.x;
                part += (acc[mt][1] + tv.y) * pv.y;
                part += (acc[mt][2] + tv.z) * pv.z;
                part += (acc[mt][3] + tv.w) * pv.w;
            }
            part += __shfl_xor(part, 16, 64);
            part += __shfl_xor(part, 32, 64);

            if (actv && q == 0) {
                if (sv < B) out[sv] = softplusf(-part);
                else atomicAdd(&ldsNeg[wave * 16 + ((sv - B) >> shiftB)], softplusf(part));
            }
        }
    }
    __syncthreads();

    // plain per-block partial stores (ws poisoned -> every block must write)
    if (tid < NS) {
        float s = ldsNeg[tid] + ldsNeg[16 + tid] + ldsNeg[32 + tid] + ldsNeg[48 + tid];
        negpart[(size_t)tid * gridN + blockIdx.x] = s;
    }
}

// ---------------- final neg reduction (one block per ns) ----------------
__global__ void k_reduce(const float* __restrict__ negpart, float* __restrict__ out,
                         int B, int gridN) {
    __shared__ float red[256];
    int ns = blockIdx.x;
    float acc = 0.f;
    for (int r = threadIdx.x; r < gridN; r += 256)
        acc += negpart[(size_t)ns * gridN + r];
    red[threadIdx.x] = acc;
    __syncthreads();
    for (int s2 = 128; s2 > 0; s2 >>= 1) {
        if (threadIdx.x < s2) red[threadIdx.x] += red[threadIdx.x + s2];
        __syncthreads();
    }
    if (threadIdx.x == 0) out[B + ns] = red[0];
}

extern "C" void kernel_launch(void* const* d_in, const int* in_sizes, int n_in,
                              void* d_out, int out_size, void* d_ws, size_t ws_size,
                              hipStream_t stream) {
    const int*   pos_u    = (const int*)d_in[0];
    const int*   pos_t    = (const int*)d_in[1];
    const int*   pos_p    = (const int*)d_in[2];
    const int*   neg_u    = (const int*)d_in[3];
    const int*   neg_t    = (const int*)d_in[4];
    const int*   neg_p    = (const int*)d_in[5];
    const float* user_emb = (const float*)d_in[7];
    const float* poi_emb  = (const float*)d_in[8];
    const float* time_emb = (const float*)d_in[9];
    const float* proj_emb = (const float*)d_in[10];
    float* out = (float*)d_out;

    const int B     = in_sizes[0];           // 4096
    const int NS    = in_sizes[3] / B;       // 10
    const int total = B + NS * B;            // 45056
    const int T     = in_sizes[9] / 128;     // 168 time slots
    const int NB    = (total + 1023) / 1024; // hist blocks (44) <= T

    int shiftB = 0;
    while ((1 << shiftB) < B) shiftB++;      // B = 4096 (pow2)

    const int gridN = T * CPB;               // k_main grid (1008)

    // workspace layout (pws first: 16B-aligned)
    unsigned short* pws = (unsigned short*)d_ws;          // [T*16384] bf16, swizzled
    int* ws_i    = (int*)((char*)d_ws + (size_t)T * 32768);
    int* hcnt    = ws_i;                                  // [T*NB]
    int* offsets = hcnt + T * NB;                         // [T+1]
    int* sorted  = offsets + T + 1;                       // [total]
    float* negpart = (float*)(sorted + total);            // [NS][gridN]

    k01_convert_hist<<<T, 1024, 0, stream>>>(proj_emb, pws, pos_t, neg_t,
                                             hcnt, B, total, T, NB);
    k3_scan_scatter<<<NB, 1024, 0, stream>>>(pos_t, neg_t, hcnt, sorted,
                                             offsets, B, total, T, NB);
    k_main<<<gridN, NTHR, 0, stream>>>(pos_u, pos_p, neg_u, neg_p,
                                       user_emb, poi_emb, time_emb, pws,
                                       offsets, sorted, out, negpart,
                                       B, shiftB, NS, gridN);
    k_reduce<<<NS, 256, 0, stream>>>(negpart, out, B, gridN);
}

// Round 11
// 165.014 us; speedup vs baseline: 1.5123x; 1.0075x over previous
//
#include <hip/hip_runtime.h>
#include <hip/hip_bf16.h>
#include <math.h>

// LBGC: log-sigmoid TransR scoring.
// pos[b]  = softplus(-s_b),  s = dot(P_t u + time_t, poi_p)
// neg[ns] = sum_b softplus(+s_{ns,b})
//
// Pipeline (4 dispatches):
//   k01: proj_emb fp32 -> bf16 (linear) into ws + per-block t-histograms
//   k3 : fused scan + scatter; block 0 also emits 16-sample tile
//        descriptors (t, rem, p0) and the tile count
//   k_main: 1 wave = 1 tile; MFMA A-fragments read DIRECTLY from L2/L3-
//        resident bf16 P (no LDS staging, no barriers); u/poi/time gathered;
//        neg partials via tiny per-wave LDS -> negpart[ns][block]
//   k_reduce: sum per-block neg partials (one block per ns).

typedef __attribute__((ext_vector_type(8))) short bfx8;
typedef __attribute__((ext_vector_type(4))) float f32x4;

#define NTHR 256  // 4 waves per block (k_main)

__device__ __forceinline__ float softplusf(float x) {
    return fmaxf(x, 0.f) + log1pf(expf(-fabsf(x)));
}

// f32 -> bf16 bits, round-to-nearest-even
__device__ __forceinline__ unsigned short f2bf(float f) {
    unsigned u = __float_as_uint(f);
    unsigned r = u + 0x7FFFu + ((u >> 16) & 1u);
    return (unsigned short)(r >> 16);
}

// ---------------- k01: P fp32 -> bf16 linear (+ histogram on low blocks) ----
__global__ __launch_bounds__(1024) void k01_convert_hist(
    const float* __restrict__ proj_emb, unsigned short* __restrict__ pws,
    const int* __restrict__ pos_t, const int* __restrict__ neg_t,
    int* __restrict__ hcnt, int B, int total, int T, int NB) {
    __shared__ int h[256];
    const int t   = blockIdx.x;
    const int tid = threadIdx.x;

    if (tid < 256) h[tid] = 0;

    const float* Pg = proj_emb + (size_t)t * 16384;
    unsigned short* dst = pws + (size_t)t * 16384;
    #pragma unroll
    for (int it = 0; it < 4; ++it) {
        int o = (it * 1024 + tid) * 4;
        float4 v = *(const float4*)(Pg + o);
        unsigned lo = (unsigned)f2bf(v.x) | ((unsigned)f2bf(v.y) << 16);
        unsigned hi = (unsigned)f2bf(v.z) | ((unsigned)f2bf(v.w) << 16);
        *(uint2*)(dst + o) = make_uint2(lo, hi);
    }

    __syncthreads();
    if (blockIdx.x < (unsigned)NB) {
        int s = blockIdx.x * 1024 + tid;
        if (s < total) {
            int tt = (s < B) ? pos_t[s] : neg_t[s - B];
            atomicAdd(&h[tt], 1);
        }
    }
    __syncthreads();
    if (blockIdx.x < (unsigned)NB && tid < T) hcnt[tid * NB + blockIdx.x] = h[tid];
}

// ---------------- k3: fused scan + scatter + tile descriptors ----------------
__global__ __launch_bounds__(1024) void k3_scan_scatter(
    const int* __restrict__ pos_t, const int* __restrict__ neg_t,
    const int* __restrict__ hcnt, int* __restrict__ sorted,
    int* __restrict__ offsets, int* __restrict__ tdesc, int* __restrict__ ntiles,
    int B, int total, int T, int NB) {
    __shared__ int tmp[256];
    __shared__ int cur[256];
    __shared__ int tsc[256];
    int tid = threadIdx.x;
    int tot_ = 0, pre_ = 0;
    if (tid < T) {
        for (int b = 0; b < NB; ++b) {
            int v = hcnt[tid * NB + b];
            if (b < (int)blockIdx.x) pre_ += v;
            tot_ += v;
        }
    }
    int nt_ = (tot_ + 15) >> 4;
    if (tid < 256) { tmp[tid] = tot_; tsc[tid] = nt_; }
    __syncthreads();
    for (int d = 1; d < 256; d <<= 1) {
        int v = 0, w = 0;
        if (tid < 256 && tid >= d) { v = tmp[tid - d]; w = tsc[tid - d]; }
        __syncthreads();
        if (tid < 256) { tmp[tid] += v; tsc[tid] += w; }
        __syncthreads();
    }
    if (tid < T) {
        int excl = tmp[tid] - tot_;           // bin start in sorted order
        cur[tid] = excl + pre_;               // this block's scatter base
        if (blockIdx.x == 0) {
            offsets[tid] = excl;
            if (tid == T - 1) { offsets[T] = tmp[tid]; *ntiles = tsc[tid]; }
            int tb = tsc[tid] - nt_;          // tile base for this bin
            for (int i = 0; i < nt_; ++i) {
                int rem = tot_ - 16 * i; if (rem > 16) rem = 16;
                tdesc[tb + i] = (tid << 21) | (rem << 16) | (excl + 16 * i);
            }
        }
    }
    __syncthreads();
    int s = blockIdx.x * 1024 + tid;
    if (s < total) {
        int t = (s < B) ? pos_t[s] : neg_t[s - B];
        int r = atomicAdd(&cur[t], 1);
        sorted[r] = s;
    }
}

// ---------------- main scoring kernel (MFMA, no staging) ----------------
__global__ __launch_bounds__(NTHR) void k_main(
    const int* __restrict__ pos_u, const int* __restrict__ pos_p,
    const int* __restrict__ neg_u, const int* __restrict__ neg_p,
    const float* __restrict__ user_emb, const float* __restrict__ poi_emb,
    const float* __restrict__ time_emb, const unsigned short* __restrict__ pws,
    const int* __restrict__ sorted, const int* __restrict__ tdesc,
    const int* __restrict__ ntiles_p,
    float* __restrict__ out, float* __restrict__ negpart,
    int B, int shiftB, int NS, int gridN)
{
    __shared__ float ldsNeg[4 * 16];

    const int tid  = threadIdx.x;
    const int wave = tid >> 6;
    const int lane = tid & 63;
    const int q    = lane >> 4;   // quad 0..3 (K-slice / C-row group)
    const int n    = lane & 15;   // sample slot / A-row within tile

    if (tid < 64) ldsNeg[tid] = 0.f;
    __syncthreads();

    const int nt = *ntiles_p;
    const int ti = blockIdx.x * 4 + wave;
    if (ti < nt) {
        int d   = tdesc[ti];
        int t   = d >> 21;
        int rem = (d >> 16) & 31;
        int p0  = d & 0xFFFF;

        int p = p0 + n;
        bool actv = (n < rem);
        int sv = sorted[actv ? p : p0];
        int uidx, pidx;
        if (sv < B) { uidx = pos_u[sv]; pidx = pos_p[sv]; }
        else        { int r = sv - B; uidx = neg_u[r]; pidx = neg_p[r]; }

        // B-fragments: u row -> bf16, lane holds k = kk*32 + q*8 .. +7
        const float* up = user_emb + (size_t)uidx * 128;
        bfx8 ub[4];
        #pragma unroll
        for (int kk = 0; kk < 4; ++kk) {
            const float* usrc = up + kk * 32 + q * 8;
            float4 a = *(const float4*)(usrc);
            float4 b = *(const float4*)(usrc + 4);
            bfx8 f;
            f[0] = (short)f2bf(a.x); f[1] = (short)f2bf(a.y);
            f[2] = (short)f2bf(a.z); f[3] = (short)f2bf(a.w);
            f[4] = (short)f2bf(b.x); f[5] = (short)f2bf(b.y);
            f[6] = (short)f2bf(b.z); f[7] = (short)f2bf(b.w);
            ub[kk] = f;
        }

        f32x4 acc[8];
        #pragma unroll
        for (int mt = 0; mt < 8; ++mt) acc[mt] = (f32x4)(0.f);

        // V = P * U : A-fragments straight from L2/L3-resident bf16 P.
        // lane (q,n) reads row mt*16+n, bytes kk*64 + q*16 (64B-coalesced).
        const char* Pt = (const char*)pws + (size_t)t * 32768;
        #pragma unroll
        for (int mt = 0; mt < 8; ++mt) {
            #pragma unroll
            for (int kk = 0; kk < 4; ++kk) {
                bfx8 af = *(const bfx8*)(Pt + (size_t)(mt * 16 + n) * 256 + kk * 64 + q * 16);
                acc[mt] = __builtin_amdgcn_mfma_f32_16x16x32_bf16(af, ub[kk], acc[mt], 0, 0, 0);
            }
        }

        // epilogue: score = sum_m (V[m][n] + time[m]) * poi[m]
        // C/D layout: col = lane&15 (sample), row = (lane>>4)*4 + reg
        const float* pp = poi_emb + (size_t)pidx * 128;
        const float* tp = time_emb + (size_t)t * 128;
        float part = 0.f;
        #pragma unroll
        for (int mt = 0; mt < 8; ++mt) {
            int mo = mt * 16 + q * 4;
            float4 pv = *(const float4*)(pp + mo);
            float4 tv = *(const float4*)(tp + mo);
            part += (acc[mt][0] + tv.x) * pv.x;
            part += (acc[mt][1] + tv.y) * pv.y;
            part += (acc[mt][2] + tv.z) * pv.z;
            part += (acc[mt][3] + tv.w) * pv.w;
        }
        part += __shfl_xor(part, 16, 64);
        part += __shfl_xor(part, 32, 64);

        if (actv && q == 0) {
            if (sv < B) out[sv] = softplusf(-part);
            else atomicAdd(&ldsNeg[wave * 16 + ((sv - B) >> shiftB)], softplusf(part));
        }
    }
    __syncthreads();

    // plain per-block partial stores (ws poisoned -> every block must write)
    if (tid < NS) {
        float s = ldsNeg[tid] + ldsNeg[16 + tid] + ldsNeg[32 + tid] + ldsNeg[48 + tid];
        negpart[(size_t)tid * gridN + blockIdx.x] = s;
    }
}

// ---------------- final neg reduction (one block per ns) ----------------
__global__ void k_reduce(const float* __restrict__ negpart, float* __restrict__ out,
                         int B, int gridN) {
    __shared__ float red[256];
    int ns = blockIdx.x;
    float acc = 0.f;
    for (int r = threadIdx.x; r < gridN; r += 256)
        acc += negpart[(size_t)ns * gridN + r];
    red[threadIdx.x] = acc;
    __syncthreads();
    for (int s2 = 128; s2 > 0; s2 >>= 1) {
        if (threadIdx.x < s2) red[threadIdx.x] += red[threadIdx.x + s2];
        __syncthreads();
    }
    if (threadIdx.x == 0) out[B + ns] = red[0];
}

extern "C" void kernel_launch(void* const* d_in, const int* in_sizes, int n_in,
                              void* d_out, int out_size, void* d_ws, size_t ws_size,
                              hipStream_t stream) {
    const int*   pos_u    = (const int*)d_in[0];
    const int*   pos_t    = (const int*)d_in[1];
    const int*   pos_p    = (const int*)d_in[2];
    const int*   neg_u    = (const int*)d_in[3];
    const int*   neg_t    = (const int*)d_in[4];
    const int*   neg_p    = (const int*)d_in[5];
    const float* user_emb = (const float*)d_in[7];
    const float* poi_emb  = (const float*)d_in[8];
    const float* time_emb = (const float*)d_in[9];
    const float* proj_emb = (const float*)d_in[10];
    float* out = (float*)d_out;

    const int B     = in_sizes[0];           // 4096
    const int NS    = in_sizes[3] / B;       // 10
    const int total = B + NS * B;            // 45056
    const int T     = in_sizes[9] / 128;     // 168 time slots
    const int NB    = (total + 1023) / 1024; // hist blocks (44) <= T

    int shiftB = 0;
    while ((1 << shiftB) < B) shiftB++;      // B = 4096 (pow2)

    const int maxTiles = (total + 15) / 16 + T;     // 2984 upper bound
    const int gridMain = (maxTiles + 3) / 4;        // 746 blocks, 1 wave = 1 tile

    // workspace layout (pws first: 16B-aligned)
    unsigned short* pws = (unsigned short*)d_ws;          // [T*16384] bf16, linear
    int* ws_i    = (int*)((char*)d_ws + (size_t)T * 32768);
    int* hcnt    = ws_i;                                  // [T*NB]
    int* offsets = hcnt + T * NB;                         // [T+1]
    int* sorted  = offsets + T + 1;                       // [total]
    int* tdesc   = sorted + total;                        // [maxTiles]
    int* ntiles  = tdesc + maxTiles;                      // [1]
    float* negpart = (float*)(ntiles + 3);                // [NS][gridMain]

    k01_convert_hist<<<T, 1024, 0, stream>>>(proj_emb, pws, pos_t, neg_t,
                                             hcnt, B, total, T, NB);
    k3_scan_scatter<<<NB, 1024, 0, stream>>>(pos_t, neg_t, hcnt, sorted,
                                             offsets, tdesc, ntiles,
                                             B, total, T, NB);
    k_main<<<gridMain, NTHR, 0, stream>>>(pos_u, pos_p, neg_u, neg_p,
                                          user_emb, poi_emb, time_emb, pws,
                                          sorted, tdesc, ntiles,
                                          out, negpart, B, shiftB, NS, gridMain);
    k_reduce<<<NS, 256, 0, stream>>>(negpart, out, B, gridMain);
}